// Round 1
// baseline (1023.769 us; speedup 1.0000x reference)
//
#include <hip/hip_runtime.h>

#define NN 50000
#define NE 800000

typedef _Float16 f16;
typedef _Float16 f16x8 __attribute__((ext_vector_type(8)));
typedef float f32x4 __attribute__((ext_vector_type(4)));

__device__ __forceinline__ f16x8 fzero8() {
  f16x8 v;
#pragma unroll
  for (int i = 0; i < 8; ++i) v[i] = (f16)0.f;
  return v;
}

__device__ __forceinline__ f32x4 mfma16(f16x8 a, f16x8 b, f32x4 c) {
  return __builtin_amdgcn_mfma_f32_16x16x32_f16(a, b, c, 0, 0, 0);
}

// ---------------- prep kernels ----------------

__global__ void count_kernel(const int* __restrict__ dst, int* __restrict__ cnt) {
  int e = blockIdx.x * 256 + threadIdx.x;
  if (e < NE) atomicAdd(&cnt[dst[e]], 1);
}

__global__ void inv_kernel(const int* __restrict__ cnt, float* __restrict__ inv) {
  int n = blockIdx.x * 256 + threadIdx.x;
  if (n < NN) inv[n] = 1.0f / fmaxf((float)cnt[n], 1.0f);
}

// W is [K_src][Nw] row-major f32; writes out[n*Kd + kd + kk] = W[(ks+kk)*Nw + n]
__global__ void prep_w(const float* __restrict__ W, int Nw, f16* __restrict__ out,
                       int Kd, int ks, int kd, int klen, int nc) {
  int idx = blockIdx.x * 256 + threadIdx.x;
  if (idx >= klen * nc) return;
  int kk = idx / nc, n = idx % nc;
  out[n * Kd + kd + kk] = (f16)W[(ks + kk) * Nw + n];
}

// packed encoder edge input rows: [x_src(5) | x_dst(5) | ea(4) | 0 0] as f16[16]
__global__ void enc_pack(const float* __restrict__ x, const float* __restrict__ ea,
                         const int* __restrict__ src, const int* __restrict__ dst,
                         f16* __restrict__ A) {
  int e = blockIdx.x * 256 + threadIdx.x;
  if (e >= NE) return;
  int s = src[e], d = dst[e];
  f16 row[16];
#pragma unroll
  for (int i = 0; i < 5; ++i) { row[i] = (f16)x[s * 5 + i]; row[5 + i] = (f16)x[d * 5 + i]; }
#pragma unroll
  for (int i = 0; i < 4; ++i) row[10 + i] = (f16)ea[e * 4 + i];
  row[14] = (f16)0.f; row[15] = (f16)0.f;
  *(f16x8*)(A + (size_t)e * 16) = *(f16x8*)row;
  *(f16x8*)(A + (size_t)e * 16 + 8) = *(f16x8*)(row + 8);
}

__global__ void agg_finish(const float* __restrict__ agg, const float* __restrict__ inv,
                           f16* __restrict__ aggh) {
  int i = blockIdx.x * 256 + threadIdx.x;  // grid sized exactly NN*64
  aggh[i] = (f16)(agg[i] * inv[i >> 6]);
}

// ---------------- edge MLP ----------------
// STAGE: 0=encoder (A from packed Aenc, write el, no residual)
//        1=processor (A=[xh[src]|xh[dst]|el], el += ed in place)
//        2=decoder   (A same as proc, no el write)
// All stages atomically accumulate ed into agg[dst].
template <int STAGE, int KT1>
__global__ void edge_mlp_kernel(const f16* __restrict__ Aenc,
                                const f16* __restrict__ xh,
                                const f16* el, f16* elw,
                                const int* __restrict__ src,
                                const int* __restrict__ dstv,
                                const f16* __restrict__ B1,
                                const f16* __restrict__ B2,
                                const float* __restrict__ b1,
                                const float* __restrict__ b2,
                                float* __restrict__ agg) {
  constexpr int K1 = KT1 * 32;
  __shared__ __align__(16) f16 h1s[4][16][72];
  const int wave = threadIdx.x >> 6;
  const int lane = threadIdx.x & 63;
  const int l15 = lane & 15, lg = lane >> 4;
  const int nwaves = gridDim.x * 4;
  const int wid = blockIdx.x * 4 + wave;
  const int NG = NE / 16;

  f16x8 B1f[KT1][4];
#pragma unroll
  for (int kk = 0; kk < KT1; ++kk)
#pragma unroll
    for (int nt = 0; nt < 4; ++nt)
      B1f[kk][nt] = *(const f16x8*)(B1 + (nt * 16 + l15) * K1 + kk * 32 + lg * 8);
  f16x8 B2f[2][4];
#pragma unroll
  for (int kk = 0; kk < 2; ++kk)
#pragma unroll
    for (int nt = 0; nt < 4; ++nt)
      B2f[kk][nt] = *(const f16x8*)(B2 + (nt * 16 + l15) * 64 + kk * 32 + lg * 8);
  float bias1[4], bias2[4];
#pragma unroll
  for (int nt = 0; nt < 4; ++nt) { bias1[nt] = b1[nt * 16 + l15]; bias2[nt] = b2[nt * 16 + l15]; }

  const int nIter = (NG + nwaves - 1) / nwaves;
  for (int it = 0; it < nIter; ++it) {
    const int g = wid + it * nwaves;
    const bool act = g < NG;
    const int e0 = g * 16;

    f32x4 acc[4];
#pragma unroll
    for (int nt = 0; nt < 4; ++nt) { acc[nt][0] = 0.f; acc[nt][1] = 0.f; acc[nt][2] = 0.f; acc[nt][3] = 0.f; }

    if (act) {
      const int erA = e0 + l15;
      if (STAGE == 0) {
        f16x8 a = fzero8();
        if (lg < 2) a = *(const f16x8*)(Aenc + (size_t)erA * 16 + lg * 8);
#pragma unroll
        for (int nt = 0; nt < 4; ++nt) acc[nt] = mfma16(a, B1f[0][nt], acc[nt]);
      } else {
        const int s = src[erA];
        const int d = dstv[erA];
#pragma unroll
        for (int kk = 0; kk < KT1; ++kk) {
          const f16* base = (kk < 2) ? (xh + (size_t)s * 64 + kk * 32)
                          : (kk < 4) ? (xh + (size_t)d * 64 + (kk - 2) * 32)
                                     : (el + (size_t)erA * 64 + (kk - 4) * 32);
          f16x8 a = *(const f16x8*)(base + lg * 8);
#pragma unroll
          for (int nt = 0; nt < 4; ++nt) acc[nt] = mfma16(a, B1f[kk][nt], acc[nt]);
        }
      }
      // bias + relu, stage h1 to LDS for layout transpose (C-layout -> A-layout)
#pragma unroll
      for (int nt = 0; nt < 4; ++nt)
#pragma unroll
        for (int r = 0; r < 4; ++r) {
          float h = fmaxf(acc[nt][r] + bias1[nt], 0.f);
          h1s[wave][lg * 4 + r][nt * 16 + l15] = (f16)h;
        }
    }
    __syncthreads();
    f32x4 out[4];
#pragma unroll
    for (int nt = 0; nt < 4; ++nt) { out[nt][0] = 0.f; out[nt][1] = 0.f; out[nt][2] = 0.f; out[nt][3] = 0.f; }
    if (act) {
#pragma unroll
      for (int kk = 0; kk < 2; ++kk) {
        f16x8 hf = *(const f16x8*)&h1s[wave][l15][kk * 32 + lg * 8];
#pragma unroll
        for (int nt = 0; nt < 4; ++nt) out[nt] = mfma16(hf, B2f[kk][nt], out[nt]);
      }
#pragma unroll
      for (int r = 0; r < 4; ++r) {
        const int er = e0 + lg * 4 + r;
        const int dn = dstv[er];
#pragma unroll
        for (int nt = 0; nt < 4; ++nt) {
          const int col = nt * 16 + l15;
          float v = out[nt][r] + bias2[nt];
          if (STAGE == 0) {
            elw[(size_t)er * 64 + col] = (f16)v;
          } else if (STAGE == 1) {
            float eo = (float)el[(size_t)er * 64 + col];
            elw[(size_t)er * 64 + col] = (f16)(eo + v);
          }
          atomicAdd(agg + (size_t)dn * 64 + col, v);
        }
      }
    }
    __syncthreads();
  }
}

// ---------------- node MLP ----------------
// STAGE: 0=encoder (A=[x_raw(5,pad32)|aggh], out: xl=v, xh=f16(v))
//        1=processor (A=[xh|aggh], xl += v, xh mirror)
//        2=decoder   (A=[xh|aggh], write d_out[N][7])
template <int STAGE, int KT1, int NT2, int OUTW>
__global__ void node_mlp_kernel(const float* __restrict__ xraw,
                                const f16* xh,
                                const f16* __restrict__ aggh,
                                const f16* __restrict__ B1,
                                const f16* __restrict__ B2,
                                const float* __restrict__ b1,
                                const float* __restrict__ b2,
                                float* __restrict__ xl,
                                f16* xho,
                                float* __restrict__ outp) {
  constexpr int K1 = KT1 * 32;
  __shared__ __align__(16) f16 h1s[4][16][72];
  const int wave = threadIdx.x >> 6;
  const int lane = threadIdx.x & 63;
  const int l15 = lane & 15, lg = lane >> 4;
  const int nwaves = gridDim.x * 4;
  const int wid = blockIdx.x * 4 + wave;
  const int NG = NN / 16;

  f16x8 B1f[KT1][4];
#pragma unroll
  for (int kk = 0; kk < KT1; ++kk)
#pragma unroll
    for (int nt = 0; nt < 4; ++nt)
      B1f[kk][nt] = *(const f16x8*)(B1 + (nt * 16 + l15) * K1 + kk * 32 + lg * 8);
  f16x8 B2f[2][NT2];
#pragma unroll
  for (int kk = 0; kk < 2; ++kk)
#pragma unroll
    for (int nt = 0; nt < NT2; ++nt)
      B2f[kk][nt] = *(const f16x8*)(B2 + (nt * 16 + l15) * 64 + kk * 32 + lg * 8);
  float bias1[4], bias2[NT2];
#pragma unroll
  for (int nt = 0; nt < 4; ++nt) bias1[nt] = b1[nt * 16 + l15];
#pragma unroll
  for (int nt = 0; nt < NT2; ++nt) bias2[nt] = (nt * 16 + l15 < OUTW) ? b2[nt * 16 + l15] : 0.f;

  const int nIter = (NG + nwaves - 1) / nwaves;
  for (int it = 0; it < nIter; ++it) {
    const int g = wid + it * nwaves;
    const bool act = g < NG;
    const int n0 = g * 16;

    f32x4 acc[4];
#pragma unroll
    for (int nt = 0; nt < 4; ++nt) { acc[nt][0] = 0.f; acc[nt][1] = 0.f; acc[nt][2] = 0.f; acc[nt][3] = 0.f; }

    if (act) {
      const int rA = n0 + l15;
#pragma unroll
      for (int kk = 0; kk < KT1; ++kk) {
        f16x8 a;
        if (STAGE == 0) {
          if (kk == 0) {
            a = fzero8();
            if (lg == 0) {
#pragma unroll
              for (int j = 0; j < 5; ++j) a[j] = (f16)xraw[(size_t)rA * 5 + j];
            }
          } else {
            a = *(const f16x8*)(aggh + (size_t)rA * 64 + (kk - 1) * 32 + lg * 8);
          }
        } else {
          a = (kk < 2) ? *(const f16x8*)(xh + (size_t)rA * 64 + kk * 32 + lg * 8)
                       : *(const f16x8*)(aggh + (size_t)rA * 64 + (kk - 2) * 32 + lg * 8);
        }
#pragma unroll
        for (int nt = 0; nt < 4; ++nt) acc[nt] = mfma16(a, B1f[kk][nt], acc[nt]);
      }
#pragma unroll
      for (int nt = 0; nt < 4; ++nt)
#pragma unroll
        for (int r = 0; r < 4; ++r) {
          float h = fmaxf(acc[nt][r] + bias1[nt], 0.f);
          h1s[wave][lg * 4 + r][nt * 16 + l15] = (f16)h;
        }
    }
    __syncthreads();
    f32x4 out[NT2];
#pragma unroll
    for (int nt = 0; nt < NT2; ++nt) { out[nt][0] = 0.f; out[nt][1] = 0.f; out[nt][2] = 0.f; out[nt][3] = 0.f; }
    if (act) {
#pragma unroll
      for (int kk = 0; kk < 2; ++kk) {
        f16x8 hf = *(const f16x8*)&h1s[wave][l15][kk * 32 + lg * 8];
#pragma unroll
        for (int nt = 0; nt < NT2; ++nt) out[nt] = mfma16(hf, B2f[kk][nt], out[nt]);
      }
#pragma unroll
      for (int r = 0; r < 4; ++r) {
        const int row = n0 + lg * 4 + r;
#pragma unroll
        for (int nt = 0; nt < NT2; ++nt) {
          const int col = nt * 16 + l15;
          float v = out[nt][r] + bias2[nt];
          if (STAGE == 0) {
            xl[(size_t)row * 64 + col] = v;
            xho[(size_t)row * 64 + col] = (f16)v;
          } else if (STAGE == 1) {
            float nv = xl[(size_t)row * 64 + col] + v;
            xl[(size_t)row * 64 + col] = nv;
            xho[(size_t)row * 64 + col] = (f16)nv;
          } else {
            if (col < OUTW) outp[(size_t)row * OUTW + col] = v;
          }
        }
      }
    }
    __syncthreads();
  }
}

// ---------------- launch ----------------

extern "C" void kernel_launch(void* const* d_in, const int* in_sizes, int n_in,
                              void* d_out, int out_size, void* d_ws, size_t ws_size,
                              hipStream_t stream) {
  const float* x  = (const float*)d_in[0];
  const int* ei   = (const int*)d_in[1];
  const float* ea = (const float*)d_in[2];
  const float* enc_e_w1 = (const float*)d_in[3];  const float* enc_e_b1 = (const float*)d_in[4];
  const float* enc_e_w2 = (const float*)d_in[5];  const float* enc_e_b2 = (const float*)d_in[6];
  const float* enc_n_w1 = (const float*)d_in[7];  const float* enc_n_b1 = (const float*)d_in[8];
  const float* enc_n_w2 = (const float*)d_in[9];  const float* enc_n_b2 = (const float*)d_in[10];
  const float* proc_e_w1 = (const float*)d_in[11]; const float* proc_e_b1 = (const float*)d_in[12];
  const float* proc_e_w2 = (const float*)d_in[13]; const float* proc_e_b2 = (const float*)d_in[14];
  const float* proc_n_w1 = (const float*)d_in[15]; const float* proc_n_b1 = (const float*)d_in[16];
  const float* proc_n_w2 = (const float*)d_in[17]; const float* proc_n_b2 = (const float*)d_in[18];
  const float* dec_e_w1 = (const float*)d_in[19]; const float* dec_e_b1 = (const float*)d_in[20];
  const float* dec_e_w2 = (const float*)d_in[21]; const float* dec_e_b2 = (const float*)d_in[22];
  const float* dec_n_w1 = (const float*)d_in[23]; const float* dec_n_b1 = (const float*)d_in[24];
  const float* dec_n_w2 = (const float*)d_in[25]; const float* dec_n_b2 = (const float*)d_in[26];

  const int* src = ei;
  const int* dst = ei + NE;

  char* p = (char*)d_ws;
  f16* el    = (f16*)p;   p += (size_t)NE * 64 * 2;
  f16* Aenc  = (f16*)p;   p += (size_t)NE * 16 * 2;
  float* agg = (float*)p; p += (size_t)NN * 64 * 4;
  float* xl  = (float*)p; p += (size_t)NN * 64 * 4;
  f16* xh    = (f16*)p;   p += (size_t)NN * 64 * 2;
  f16* aggh  = (f16*)p;   p += (size_t)NN * 64 * 2;
  int* cnt   = (int*)p;   p += (size_t)NN * 4;
  float* inv = (float*)p; p += (size_t)NN * 4;
  f16* wb    = (f16*)p;
  f16* W1T_ence = wb; wb += 64 * 32;
  f16* W2T_ence = wb; wb += 64 * 64;
  f16* W1T_encn = wb; wb += 64 * 96;
  f16* W2T_encn = wb; wb += 64 * 64;
  f16* W1T_proce = wb; wb += 64 * 192;
  f16* W2T_proce = wb; wb += 64 * 64;
  f16* W1T_procn = wb; wb += 64 * 128;
  f16* W2T_procn = wb; wb += 64 * 64;
  f16* W1T_dece = wb; wb += 64 * 192;
  f16* W2T_dece = wb; wb += 64 * 64;
  f16* W1T_decn = wb; wb += 64 * 128;
  f16* W2T_decn = wb; wb += 16 * 64;
  const size_t wbytes = (size_t)((char*)wb - (char*)((f16*)p)) ;

  hipMemsetAsync(cnt, 0, (size_t)NN * 4, stream);
  hipMemsetAsync((void*)W1T_ence, 0, wbytes, stream);

  count_kernel<<<(NE + 255) / 256, 256, 0, stream>>>(dst, cnt);
  inv_kernel<<<(NN + 255) / 256, 256, 0, stream>>>(cnt, inv);

  auto PREP = [&](const float* W, int Nw, f16* outw, int Kd, int ks, int kd, int klen, int nc) {
    int tot = klen * nc;
    prep_w<<<(tot + 255) / 256, 256, 0, stream>>>(W, Nw, outw, Kd, ks, kd, klen, nc);
  };
  PREP(enc_e_w1, 64, W1T_ence, 32, 0, 0, 14, 64);
  PREP(enc_e_w2, 64, W2T_ence, 64, 0, 0, 64, 64);
  PREP(enc_n_w1, 64, W1T_encn, 96, 0, 0, 5, 64);
  PREP(enc_n_w1, 64, W1T_encn, 96, 5, 32, 64, 64);
  PREP(enc_n_w2, 64, W2T_encn, 64, 0, 0, 64, 64);
  PREP(proc_e_w1, 64, W1T_proce, 192, 0, 0, 192, 64);
  PREP(proc_e_w2, 64, W2T_proce, 64, 0, 0, 64, 64);
  PREP(proc_n_w1, 64, W1T_procn, 128, 0, 0, 128, 64);
  PREP(proc_n_w2, 64, W2T_procn, 64, 0, 0, 64, 64);
  PREP(dec_e_w1, 64, W1T_dece, 192, 0, 0, 192, 64);
  PREP(dec_e_w2, 64, W2T_dece, 64, 0, 0, 64, 64);
  PREP(dec_n_w1, 64, W1T_decn, 128, 0, 0, 128, 64);
  PREP(dec_n_w2, 7, W2T_decn, 64, 0, 0, 64, 7);

  enc_pack<<<(NE + 255) / 256, 256, 0, stream>>>(x, ea, src, dst, Aenc);

  // ---- encoder ----
  hipMemsetAsync(agg, 0, (size_t)NN * 64 * 4, stream);
  edge_mlp_kernel<0, 1><<<1024, 256, 0, stream>>>(Aenc, xh, el, el, src, dst,
                                                  W1T_ence, W2T_ence, enc_e_b1, enc_e_b2, agg);
  agg_finish<<<(NN * 64) / 256, 256, 0, stream>>>(agg, inv, aggh);
  node_mlp_kernel<0, 3, 4, 64><<<256, 256, 0, stream>>>(x, xh, aggh, W1T_encn, W2T_encn,
                                                        enc_n_b1, enc_n_b2, xl, xh, (float*)d_out);
  // ---- 2 processor rounds (shared weights, residuals) ----
  for (int r = 0; r < 2; ++r) {
    hipMemsetAsync(agg, 0, (size_t)NN * 64 * 4, stream);
    edge_mlp_kernel<1, 6><<<1024, 256, 0, stream>>>(Aenc, xh, el, el, src, dst,
                                                    W1T_proce, W2T_proce, proc_e_b1, proc_e_b2, agg);
    agg_finish<<<(NN * 64) / 256, 256, 0, stream>>>(agg, inv, aggh);
    node_mlp_kernel<1, 4, 4, 64><<<256, 256, 0, stream>>>(x, xh, aggh, W1T_procn, W2T_procn,
                                                          proc_n_b1, proc_n_b2, xl, xh, (float*)d_out);
  }
  // ---- decoder ----
  hipMemsetAsync(agg, 0, (size_t)NN * 64 * 4, stream);
  edge_mlp_kernel<2, 6><<<1024, 256, 0, stream>>>(Aenc, xh, el, el, src, dst,
                                                  W1T_dece, W2T_dece, dec_e_b1, dec_e_b2, agg);
  agg_finish<<<(NN * 64) / 256, 256, 0, stream>>>(agg, inv, aggh);
  node_mlp_kernel<2, 4, 1, 7><<<256, 256, 0, stream>>>(x, xh, aggh, W1T_decn, W2T_decn,
                                                       dec_n_b1, dec_n_b2, xl, xh, (float*)d_out);
}